// Round 17
// baseline (139.459 us; speedup 1.0000x reference)
//
#include <hip/hip_runtime.h>
#include <hip/hip_bf16.h>

// RelativeGlobalAttention: B=2, S=2048, D=512, H=8, DH=64, MAX_SEQ=2048
// out0 = attention output (B,S,D); out1 = attn probs (B,H,S,S); concatenated.
//
// Identity: srel[l,k] = q[l].E[2047-l+k] for k<=l, else 0.
// logits = (QK^T + srel)/8; causal mask => masked probs exactly 0.
// No-max softmax: exp(v)/sum(exp(v)) == reference softmax up to fp32 rounding.
//
// R17 = R16 + global_load_lds staging (width 16): direct HBM/L2 -> LDS DMA
// removes the global->VGPR->ds_write round trip in all attn staging loops
// (K/E/V/P) and the GEMM W tile. Swizzle preserved via pre-swizzled GLOBAL
// source slot + linear LDS dest (read addresses unchanged, bit-identical).

namespace {
constexpr int kS  = 2048;
constexpr int kD  = 512;
constexpr int kH  = 8;
constexpr int kDH = 64;
constexpr int kB  = 2;

typedef __attribute__((ext_vector_type(8))) short short8;   // 8 x bf16
typedef __attribute__((ext_vector_type(4))) short short4v;  // 4 x bf16 (8B)
typedef __attribute__((ext_vector_type(4))) float f32x4;

// R15 fallback attn LDS layout (bytes)
constexpr int kKl = 0;
constexpr int kVl = 8192;
constexpr int kEl = 16384;
constexpr int kPf = 26624;
constexpr int kLs = 30976;

// R16/R17 P-store attn LDS layout (bytes). Pass A: K@0 + E@8192;
// pass B overlays V@0 + P@8192 (disjoint in time).
constexpr int pKl = 0;
constexpr int pPl = 8192;
constexpr int pEl = 8192;
constexpr int pLs = 18432;
constexpr int pLi = 18688;
constexpr int pSz = 18752;

constexpr size_t kPwsElems = (size_t)16 * 2112 * 1024;  // packed P, bf16
}

// Direct global->LDS DMA, 16B per lane. LDS dest = wave-uniform base +
// lane*16 (hardware); global src is per-lane. Size must be a literal.
#define GLOAD_LDS16(gsrc, ldst) \
    __builtin_amdgcn_global_load_lds( \
        (const __attribute__((address_space(1))) void*)(gsrc), \
        (__attribute__((address_space(3))) void*)(ldst), 16, 0, 0)

__device__ __forceinline__ f32x4 mfma16(short8 a, short8 b, f32x4 c) {
    return __builtin_amdgcn_mfma_f32_16x16x32_bf16(a, b, c, 0, 0, 0);
}

__device__ __forceinline__ short bfbits(float f) {
    __hip_bfloat16 h = __float2bfloat16(f);
    return *reinterpret_cast<short*>(&h);
}

__device__ __forceinline__ float bf2f(short b) {
    const unsigned u = (unsigned)(unsigned short)b << 16;
    return __uint_as_float(u);
}

// ---------------------------------------------------------------------------
// conv: W (512x512 fp32 row-major) -> Wt (bf16 col-major [c][k]) x4; E -> bf16
// ---------------------------------------------------------------------------
__global__ __launch_bounds__(256)
void convw_kernel(const float* __restrict__ Wq, const float* __restrict__ Wk,
                  const float* __restrict__ Wv, const float* __restrict__ Wo,
                  const float* __restrict__ E,
                  ushort* __restrict__ Wqt, ushort* __restrict__ Wkt,
                  ushort* __restrict__ Wvt, ushort* __restrict__ Wot,
                  ushort* __restrict__ eb)
{
    const int z = blockIdx.z;
    const int tid = threadIdx.x;
    if (z == 4) {   // E: 2048x64 = 131072 elems
        const int idx = ((blockIdx.y * 8 + blockIdx.x) * 256 + tid) * 8;
        const float4 x = *reinterpret_cast<const float4*>(E + idx);
        const float4 y = *reinterpret_cast<const float4*>(E + idx + 4);
        short8 r;
        r[0] = bfbits(x.x); r[1] = bfbits(x.y); r[2] = bfbits(x.z); r[3] = bfbits(x.w);
        r[4] = bfbits(y.x); r[5] = bfbits(y.y); r[6] = bfbits(y.z); r[7] = bfbits(y.w);
        *reinterpret_cast<short8*>(eb + idx) = r;
        return;
    }
    const float* W = (z == 0) ? Wq : (z == 1) ? Wk : (z == 2) ? Wv : Wo;
    ushort* Wt = (z == 0) ? Wqt : (z == 1) ? Wkt : (z == 2) ? Wvt : Wot;

    __shared__ float Ws[64][65];
    const int k0 = blockIdx.x * 64;
    const int c0 = blockIdx.y * 64;
    const int cc = tid & 63;
    const int rq = tid >> 6;
    #pragma unroll
    for (int ii = 0; ii < 16; ++ii) {
        const int r = ii * 4 + rq;
        Ws[r][cc] = W[(size_t)(k0 + r) * kD + c0 + cc];
    }
    __syncthreads();
    #pragma unroll
    for (int ii = 0; ii < 16; ++ii) {
        const int r = ii * 4 + rq;
        Wt[(size_t)(c0 + r) * kD + k0 + cc] = (ushort)bfbits(Ws[cc][r]);
    }
}

// ---------------------------------------------------------------------------
// LDS-staged MFMA GEMM (R15 structure; W tile now via global_load_lds)
// ---------------------------------------------------------------------------
template<int MODE, bool AF32>
__device__ __forceinline__
void gemm_lds_core(char* lds, const void* __restrict__ Av,
                   const ushort* __restrict__ Wt,
                   const float* __restrict__ bias, void* __restrict__ out)
{
    char* As = lds;
    char* Ws = lds + 8192;

    const int tid  = threadIdx.x;
    const int w    = tid >> 6;
    const int lane = tid & 63;
    const int g    = lane >> 4;
    const int n15  = lane & 15;
    const int r0   = blockIdx.x * 64;
    const int c0   = blockIdx.y * 32;

    f32x4 acc0 = {0.f, 0.f, 0.f, 0.f};
    f32x4 acc1 = {0.f, 0.f, 0.f, 0.f};

    const int rA  = w * 16 + n15;
    const int swA = (n15 & 7) << 4;
    const int swB = (n15 & 7) << 4;

    for (int kb = 0; kb < 8; ++kb) {
        const int k0 = kb * 64;
        __syncthreads();
        #pragma unroll
        for (int hh = 0; hh < 2; ++hh) {
            const int c = tid + hh * 256;
            const int row = c >> 3, i = c & 7;
            short8 v;
            if (AF32) {
                const float* src = (const float*)Av + (size_t)(r0 + row) * kD + k0 + i * 8;
                const float4 x = *reinterpret_cast<const float4*>(src);
                const float4 y = *reinterpret_cast<const float4*>(src + 4);
                v[0] = bfbits(x.x); v[1] = bfbits(x.y); v[2] = bfbits(x.z); v[3] = bfbits(x.w);
                v[4] = bfbits(y.x); v[5] = bfbits(y.y); v[6] = bfbits(y.z); v[7] = bfbits(y.w);
            } else {
                v = *reinterpret_cast<const short8*>(
                    (const ushort*)Av + (size_t)(r0 + row) * kD + k0 + i * 8);
            }
            *reinterpret_cast<short8*>(As + row * 128 + ((i * 16) ^ ((row & 7) << 4))) = v;
        }
        {   // W tile via global_load_lds: pre-swizzled src, linear LDS dest
            const int crow = tid >> 3, i = tid & 7;
            GLOAD_LDS16(Wt + (size_t)(c0 + crow) * kD + k0 + ((i ^ (crow & 7)) * 8),
                        Ws + (tid & ~63) * 16);
        }
        __syncthreads();

        #pragma unroll
        for (int ks = 0; ks < 2; ++ks) {
            const int bo = ks * 64 + g * 16;
            const short8 a  = *reinterpret_cast<const short8*>(As + rA * 128 + (bo ^ swA));
            const short8 b0 = *reinterpret_cast<const short8*>(Ws + n15 * 128 + (bo ^ swB));
            const short8 b1 = *reinterpret_cast<const short8*>(Ws + (16 + n15) * 128 + (bo ^ swB));
            acc0 = mfma16(a, b0, acc0);
            acc1 = mfma16(a, b1, acc1);
        }
    }

    #pragma unroll
    for (int cg = 0; cg < 2; ++cg) {
        const f32x4 acc = cg ? acc1 : acc0;
        const int c = c0 + cg * 16 + n15;
        const float bb = bias[c];
        const int h = c >> 6, d = c & (kDH - 1);
        #pragma unroll
        for (int j = 0; j < 4; ++j) {
            const int r = r0 + w * 16 + g * 4 + j;
            const float val = acc[j] + bb;
            const int b = r >> 11, s2 = r & (kS - 1);
            if (MODE == 0) {
                ((float*)out)[(size_t)r * kD + c] = val;
            } else if (MODE == 1) {
                ((ushort*)out)[((size_t)(b * kH + h) * kS + s2) * kDH + d] = (ushort)bfbits(val);
            } else {
                ((ushort*)out)[((size_t)(b * kH + h) * kDH + d) * kS + s2] = (ushort)bfbits(val);
            }
        }
    }
}

__global__ __launch_bounds__(256)
void gemm_qkv_kernel(const float* __restrict__ q_in, const float* __restrict__ k_in,
                     const float* __restrict__ v_in,
                     const ushort* __restrict__ Wqt, const ushort* __restrict__ Wkt,
                     const ushort* __restrict__ Wvt,
                     const float* __restrict__ bq, const float* __restrict__ bk,
                     const float* __restrict__ bv,
                     ushort* __restrict__ qh, ushort* __restrict__ kh,
                     ushort* __restrict__ vt)
{
    __shared__ __align__(16) char lds[12288];
    const int z = blockIdx.z;
    const float*  A    = (z == 0) ? q_in : (z == 1) ? k_in : v_in;
    const ushort* Wt   = (z == 0) ? Wqt  : (z == 1) ? Wkt  : Wvt;
    const float*  bias = (z == 0) ? bq   : (z == 1) ? bk   : bv;
    void*         out  = (z == 0) ? (void*)qh : (z == 1) ? (void*)kh : (void*)vt;
    if (z == 2) gemm_lds_core<2, true>(lds, A, Wt, bias, out);
    else        gemm_lds_core<1, true>(lds, A, Wt, bias, out);
}

__global__ __launch_bounds__(256)
void gemm_o_kernel(const ushort* __restrict__ ohb, const ushort* __restrict__ Wot,
                   const float* __restrict__ bo, float* __restrict__ out)
{
    __shared__ __align__(16) char lds[12288];
    gemm_lds_core<0, false>(lds, ohb, Wot, bo, out);
}

// ---------------------------------------------------------------------------
// R17 attention with P-store + global_load_lds staging.
// Block = (bh, 16-row strip), 4 waves. Pass A: stage K/E (DMA), scores once,
// bf16 exp -> packed ws, lsum. Pass B: stage V + P tile (DMA), emit
// attn = P*linv, PV on bf16 P, O scaled at epilogue. grid (16,128) x 256.
// ---------------------------------------------------------------------------
__global__ __launch_bounds__(256, 6)
void attn_ps_kernel(const ushort* __restrict__ qh, const ushort* __restrict__ khp,
                    const ushort* __restrict__ vt, const ushort* __restrict__ eb,
                    float* __restrict__ attn, ushort* __restrict__ ohb,
                    ushort* __restrict__ Pws)
{
    __shared__ __align__(16) char smem[pSz];
    float* lsum_s = (float*)(smem + pLs);
    float* linv_s = (float*)(smem + pLi);

    const int bh    = blockIdx.x;
    const int strip = 127 - (int)blockIdx.y;     // big-work-first
    const int l0    = strip * 16;
    const int tid   = threadIdx.x;
    const int w     = tid >> 6;
    const int lane  = tid & 63;
    const int g     = lane >> 4;
    const int n15   = lane & 15;
    const size_t bhS = (size_t)bh * kS;

    const int T = (strip >> 2) + 1;              // causal 64-wide tiles

    // packed P base: sum_{s'<strip} T(s')
    const int pa_ = strip >> 2, pb_ = strip & 3;
    const int pbase = strip + 2 * pa_ * (pa_ - 1) + pa_ * pb_;
    ushort* Pstrip = Pws + ((size_t)bh * 2112 + pbase) * 1024;

    const ushort* qrow = qh + (bhS + l0 + n15) * kDH;
    const short8 aq0 = *reinterpret_cast<const short8*>(qrow + g * 8);
    const short8 aq1 = *reinterpret_cast<const short8*>(qrow + 32 + g * 8);

    int  srcl[4];
    bool condj[4];
    #pragma unroll
    for (int j = 0; j < 4; ++j) {
        const int d = n15 + 15 - (g * 4 + j);
        srcl[j]  = (lane & 48) | (d & 15);
        condj[j] = (d >= 16);
    }

    const int rW = w * 16 + n15;                 // K/V LDS row
    const int mS = (n15 & 7) << 4;
    const int b0 = (g * 16) ^ mS;
    const int b1 = (64 + g * 16) ^ mS;
    const int pcol = w * 16 + n15;               // this thread's P column

    // ---------------- pass A: scores once -> P store + lsum ----------------
    float lsum[4] = {0.f, 0.f, 0.f, 0.f};
    for (int t = 0; t < T; ++t) {
        const int k0 = t * 64;
        const int m_lo = 2032 + k0 - l0;
        __syncthreads();                         // prior tile's LDS reads done
        // stage K via DMA: pre-swizzled global slot, linear LDS
        for (int c = tid; c < 512; c += 256) {
            const int row = c >> 3, i = c & 7;
            GLOAD_LDS16(khp + (bhS + k0 + row) * kDH + ((i ^ (row & 7)) * 8),
                        smem + pKl + (c & ~63) * 16);
        }
        // stage E window via DMA (clamped rows feed masked elems only)
        for (int c = tid; c < 640; c += 256) {
            const int row = c >> 3, i = c & 7;
            const int er = min(m_lo + row, kS - 1);
            GLOAD_LDS16(eb + (size_t)er * kDH + ((i ^ (row & 7)) * 8),
                        smem + pEl + (c & ~63) * 16);
        }
        __syncthreads();                         // DMA drained + visible

        f32x4 s4 = {0.f, 0.f, 0.f, 0.f};
        s4 = mfma16(aq0, *reinterpret_cast<const short8*>(smem + pKl + rW * 128 + b0), s4);
        s4 = mfma16(aq1, *reinterpret_cast<const short8*>(smem + pKl + rW * 128 + b1), s4);
        f32x4 qe2[2];
        #pragma unroll
        for (int q2 = 0; q2 < 2; ++q2) {
            const int rE = w * 16 + q2 * 16 + n15;
            f32x4 acc = {0.f, 0.f, 0.f, 0.f};
            acc = mfma16(aq0, *reinterpret_cast<const short8*>(smem + pEl + rE * 128 + b0), acc);
            qe2[q2] = mfma16(aq1, *reinterpret_cast<const short8*>(smem + pEl + rE * 128 + b1), acc);
        }
        ushort* ptile = Pstrip + (size_t)t * 1024;
        #pragma unroll
        for (int j = 0; j < 4; ++j) {
            const float sh0 = __shfl(qe2[0][j], srcl[j]);
            const float sh1 = __shfl(qe2[1][j], srcl[j]);
            const float rel = condj[j] ? sh1 : sh0;
            float v = (s4[j] + rel) * 0.125f;
            v = fminf(v, 60.f);
            const bool keep = (k0 + pcol <= l0 + g * 4 + j);
            const float pe = keep ? __expf(v) : 0.f;
            const short pb = bfbits(pe);
            lsum[j] += bf2f(pb);                 // bf16-consistent normalization
            ptile[(g * 4 + j) * 64 + pcol] = (ushort)pb;
        }
    }
    #pragma unroll
    for (int j = 0; j < 4; ++j) {
        float s = lsum[j];
        #pragma unroll
        for (int off = 1; off < 16; off <<= 1) s += __shfl_xor(s, off);
        if (n15 == 0) lsum_s[w * 16 + g * 4 + j] = s;
    }
    __syncthreads();                             // lsum exchange
    if (tid < 16)
        linv_s[tid] = 1.f / (lsum_s[tid] + lsum_s[16 + tid] +
                             lsum_s[32 + tid] + lsum_s[48 + tid]);
    __syncthreads();                             // linv visible

    // ---------------- pass B: emit + PV (no score recompute) ----------------
    f32x4 o = {0.f, 0.f, 0.f, 0.f};
    const int srow = tid >> 4;
    const int scol = (tid & 15) * 4;
    const int sby  = ((tid & 15) * 8) ^ ((srow & 7) << 4);   // swizzled 8B pos

    for (int t = 0; t < 32; ++t) {
        const int k0 = t * 64;
        if (t >= T) {                            // fully masked: zero-fill
            const f32x4 z = {0.f, 0.f, 0.f, 0.f};
            __builtin_nontemporal_store(
                z, reinterpret_cast<f32x4*>(attn + (bhS + l0 + srow) * kS + k0 + scol));
            continue;
        }
        __syncthreads();                         // prior tile's LDS reads done
        // stage V^T via DMA (over K region)
        for (int c = tid; c < 512; c += 256) {
            const int row = c >> 3, i = c & 7;
            GLOAD_LDS16(vt + ((size_t)bh * kDH + row) * kS + k0 + ((i ^ (row & 7)) * 8),
                        smem + pKl + (c & ~63) * 16);
        }
        // stage P tile via DMA: 128 chunks (waves 0,1), pre-swizzled src
        if (tid < 128) {
            const int row = tid >> 3, i = tid & 7;
            GLOAD_LDS16(Pstrip + (size_t)t * 1024 + row * 64 + ((i ^ (row & 7)) * 8),
                        smem + pPl + (tid & ~63) * 16);
        }
        __syncthreads();                         // DMA drained + visible

        // emit: attn = bf16P * linv, 256B-contiguous row segments
        {
            const short4v pv = *reinterpret_cast<const short4v*>(smem + pPl + srow * 128 + sby);
            const float li = linv_s[srow];
            f32x4 o4;
            #pragma unroll
            for (int i = 0; i < 4; ++i) o4[i] = bf2f(pv[i]) * li;
            __builtin_nontemporal_store(
                o4, reinterpret_cast<f32x4*>(attn + (bhS + l0 + srow) * kS + k0 + scol));
        }
        // PV: A-frags straight from bf16 P LDS; B-frags from V LDS
        const short8 pa0 = *reinterpret_cast<const short8*>(smem + pPl + n15 * 128 + b0);
        const short8 pa1 = *reinterpret_cast<const short8*>(smem + pPl + n15 * 128 + b1);
        o = mfma16(pa0, *reinterpret_cast<const short8*>(smem + pKl + rW * 128 + b0), o);
        o = mfma16(pa1, *reinterpret_cast<const short8*>(smem + pKl + rW * 128 + b1), o);
    }

    // epilogue: scale O by linv, write bf16 (B,S,D)
    const int b = bh >> 3, h = bh & 7;
    #pragma unroll
    for (int j = 0; j < 4; ++j)
        ohb[((size_t)b * kS + l0 + g * 4 + j) * kD + h * kDH + w * 16 + n15] =
            (ushort)bfbits(o[j] * linv_s[g * 4 + j]);
}

// ---------------------------------------------------------------------------
// R15 attention (fallback when ws is too small) — unchanged, proven.
// ---------------------------------------------------------------------------
__global__ __launch_bounds__(256, 4)
void attn_fused_kernel(const ushort* __restrict__ qh, const ushort* __restrict__ khp,
                       const ushort* __restrict__ vt, const ushort* __restrict__ eb,
                       float* __restrict__ attn, ushort* __restrict__ ohb)
{
    __shared__ __align__(16) char smem[31232];
    float* Pf     = (float*)(smem + kPf);
    float* lsum_s = (float*)(smem + kLs);

    const int bh    = blockIdx.x;
    const int strip = 127 - (int)blockIdx.y;
    const int l0    = strip * 16;
    const int tid   = threadIdx.x;
    const int w     = tid >> 6;
    const int lane  = tid & 63;
    const int g     = lane >> 4;
    const int n15   = lane & 15;
    const size_t bhS = (size_t)bh * kS;

    const int T = ((l0 + 15) >> 6) + 1;

    const ushort* qrow = qh + (bhS + l0 + n15) * kDH;
    const short8 aq0 = *reinterpret_cast<const short8*>(qrow + g * 8);
    const short8 aq1 = *reinterpret_cast<const short8*>(qrow + 32 + g * 8);

    int  srcl[4];
    bool condj[4];
    #pragma unroll
    for (int j = 0; j < 4; ++j) {
        const int d = n15 + 15 - (g * 4 + j);
        srcl[j]  = (lane & 48) | (d & 15);
        condj[j] = (d >= 16);
    }

    const int rW = w * 16 + n15;
    const int mS = (n15 & 7) << 4;
    const int b0 = (g * 16) ^ mS;
    const int b1 = (64 + g * 16) ^ mS;

    float lsum[4] = {0.f, 0.f, 0.f, 0.f};
    for (int t = 0; t < T; ++t) {
        const int k0 = t * 64;
        const int m_lo = 2032 + k0 - l0;
        __syncthreads();
        for (int c = tid; c < 512; c += 256) {
            const int row = c >> 3, bi = (c & 7) * 16;
            const short8 v = *reinterpret_cast<const short8*>(
                khp + (bhS + k0 + row) * kDH + (c & 7) * 8);
            *reinterpret_cast<short8*>(smem + kKl + row * 128 + (bi ^ ((row & 7) << 4))) = v;
        }
        for (int c = tid; c < 640; c += 256) {
            const int row = c >> 3, bi = (c & 7) * 16;
            const int er = min(m_lo + row, kS - 1);
            const short8 v = *reinterpret_cast<const short8*>(
                eb + (size_t)er * kDH + (c & 7) * 8);
            *reinterpret_cast<short8*>(smem + kEl + row * 128 + (bi ^ ((row & 7) << 4))) = v;
        }
        __syncthreads();

        f32x4 s4 = {0.f, 0.f, 0.f, 0.f};
        s4 = mfma16(aq0, *reinterpret_cast<const short8*>(smem + kKl + rW * 128 + b0), s4);
        s4 = mfma16(aq1, *reinterpret_cast<const short8*>(smem + kKl + rW * 128 + b1), s4);
        f32x4 qe2[2];
        #pragma unroll
        for (int q2 = 0; q2 < 2; ++q2) {
            const int rE = w * 16 + q2 * 16 + n15;
            f32x4 acc = {0.f, 0.f, 0.f, 0.f};
            acc = mfma16(aq0, *reinterpret_cast<const short8*>(smem + kEl + rE * 128 + b0), acc);
            qe2[q2] = mfma16(aq1, *reinterpret_cast<const short8*>(smem + kEl + rE * 128 + b1), acc);
        }
        #pragma unroll
        for (int j = 0; j < 4; ++j) {
            const float sh0 = __shfl(qe2[0][j], srcl[j]);
            const float sh1 = __shfl(qe2[1][j], srcl[j]);
            const float rel = condj[j] ? sh1 : sh0;
            float v = (s4[j] + rel) * 0.125f;
            v = fminf(v, 60.f);
            const bool keep = (k0 + w * 16 + n15 <= l0 + g * 4 + j);
            lsum[j] += keep ? __expf(v) : 0.f;
        }
    }
    #pragma unroll
    for (int j = 0; j < 4; ++j) {
        float s = lsum[j];
        #pragma unroll
        for (int off = 1; off < 16; off <<= 1) s += __shfl_xor(s, off);
        if (n15 == 0) lsum_s[w * 16 + g * 4 + j] = s;
    }
    __syncthreads();

    float linv[4];
    #pragma unroll
    for (int j = 0; j < 4; ++j) {
        const int r = g * 4 + j;
        linv[j] = 1.f / (lsum_s[r] + lsum_s[16 + r] + lsum_s[32 + r] + lsum_s[48 + r]);
    }

    f32x4 o = {0.f, 0.f, 0.f, 0.f};
    const int srow = tid >> 4;
    const int scol = (tid & 15) * 4;

    for (int t = 0; t < 32; ++t) {
        const int k0 = t * 64;
        if (t >= T) {
            const f32x4 z = {0.f, 0.f, 0.f, 0.f};
            __builtin_nontemporal_store(
                z, reinterpret_cast<f32x4*>(attn + (bhS + l0 + srow) * kS + k0 + scol));
            continue;
        }
        const int m_lo = 2032 + k0 - l0;
        __syncthreads();
        for (int c = tid; c < 512; c += 256) {
            const int row = c >> 3, bi = (c & 7) * 16;
            const short8 v = *reinterpret_cast<const short8*>(
                khp + (bhS + k0 + row) * kDH + (c & 7) * 8);
            *reinterpret_cast<short8*>(smem + kKl + row * 128 + (bi ^ ((row & 7) << 4))) = v;
        }
        for (int c = tid; c < 512; c += 256) {
            const int row = c >> 3, bi = (c & 7) * 16;
            const short8 v = *reinterpret_cast<const short8*>(
                vt + ((size_t)bh * kDH + row) * kS + k0 + (c & 7) * 8);
            *reinterpret_cast<short8*>(smem + kVl + row * 128 + (bi ^ ((row & 7) << 4))) = v;
        }
        for (int c = tid; c < 640; c += 256) {
            const int row = c >> 3, bi = (c & 7) * 16;
            const int er = min(m_lo + row, kS - 1);
            const short8 v = *reinterpret_cast<const short8*>(
                eb + (size_t)er * kDH + (c & 7) * 8);
            *reinterpret_cast<short8*>(smem + kEl + row * 128 + (bi ^ ((row & 7) << 4))) = v;
        }
        __syncthreads();

        f32x4 s4 = {0.f, 0.f, 0.f, 0.f};
        s4 = mfma16(aq0, *reinterpret_cast<const short8*>(smem + kKl + rW * 128 + b0), s4);
        s4 = mfma16(aq1, *reinterpret_cast<const short8*>(smem + kKl + rW * 128 + b1), s4);
        f32x4 qe2[2];
        #pragma unroll
        for (int q2 = 0; q2 < 2; ++q2) {
            const int rE = w * 16 + q2 * 16 + n15;
            f32x4 acc = {0.f, 0.f, 0.f, 0.f};
            acc = mfma16(aq0, *reinterpret_cast<const short8*>(smem + kEl + rE * 128 + b0), acc);
            qe2[q2] = mfma16(aq1, *reinterpret_cast<const short8*>(smem + kEl + rE * 128 + b1), acc);
        }
        #pragma unroll
        for (int j = 0; j < 4; ++j) {
            const float sh0 = __shfl(qe2[0][j], srcl[j]);
            const float sh1 = __shfl(qe2[1][j], srcl[j]);
            const float rel = condj[j] ? sh1 : sh0;
            float v = (s4[j] + rel) * 0.125f;
            v = fminf(v, 60.f);
            const bool keep = (k0 + w * 16 + n15 <= l0 + g * 4 + j);
            const float pe = keep ? __expf(v) * linv[j] : 0.f;
            Pf[(g * 4 + j) * 68 + w * 16 + n15] = pe;
        }
        __syncthreads();

        const f32x4 pv4 = *reinterpret_cast<const f32x4*>(Pf + srow * 68 + scol);
        __builtin_nontemporal_store(
            pv4, reinterpret_cast<f32x4*>(attn + (bhS + l0 + srow) * kS + k0 + scol));

        const f32x4 plo0 = *reinterpret_cast<const f32x4*>(Pf + n15 * 68 + g * 8);
        const f32x4 phi0 = *reinterpret_cast<const f32x4*>(Pf + n15 * 68 + g * 8 + 4);
        const f32x4 plo1 = *reinterpret_cast<const f32x4*>(Pf + n15 * 68 + 32 + g * 8);
        const f32x4 phi1 = *reinterpret_cast<const f32x4*>(Pf + n15 * 68 + 32 + g * 8 + 4);
        short8 pa0, pa1;
        #pragma unroll
        for (int i = 0; i < 4; ++i) {
            pa0[i] = bfbits(plo0[i]); pa0[4 + i] = bfbits(phi0[i]);
            pa1[i] = bfbits(plo1[i]); pa1[4 + i] = bfbits(phi1[i]);
        }
        o = mfma16(pa0, *reinterpret_cast<const short8*>(smem + kVl + rW * 128 + b0), o);
        o = mfma16(pa1, *reinterpret_cast<const short8*>(smem + kVl + rW * 128 + b1), o);
    }

    const int b = bh >> 3, h = bh & 7;
    #pragma unroll
    for (int j = 0; j < 4; ++j)
        ohb[((size_t)b * kS + l0 + g * 4 + j) * kD + h * kDH + w * 16 + n15] =
            (ushort)bfbits(o[j]);
}

// ---------------------------------------------------------------------------
extern "C" void kernel_launch(void* const* d_in, const int* in_sizes, int n_in,
                              void* d_out, int out_size, void* d_ws, size_t ws_size,
                              hipStream_t stream)
{
    const float* q_in = (const float*)d_in[0];
    const float* k_in = (const float*)d_in[1];
    const float* v_in = (const float*)d_in[2];
    const float* Wq = (const float*)d_in[4];
    const float* bq = (const float*)d_in[5];
    const float* Wk = (const float*)d_in[6];
    const float* bk = (const float*)d_in[7];
    const float* Wv = (const float*)d_in[8];
    const float* bv = (const float*)d_in[9];
    const float* Wo = (const float*)d_in[10];
    const float* bo = (const float*)d_in[11];
    const float* E  = (const float*)d_in[12];

    float* out  = (float*)d_out;                          // (B,S,D)
    float* attn = (float*)d_out + (size_t)kB * kS * kD;   // (B,H,S,S)

    // workspace
    ushort* qh  = (ushort*)d_ws;          // (B,H,S,DH)
    ushort* kh  = qh  + 2097152;          // (B,H,S,DH)
    ushort* vt  = kh  + 2097152;          // (B,H,DH,S)
    ushort* ohb = vt  + 2097152;          // (B,S,D)
    ushort* eb  = ohb + 2097152;          // (2048,64)
    ushort* Wqt = eb  + 131072;           // col-major 512x512
    ushort* Wkt = Wqt + 262144;
    ushort* Wvt = Wkt + 262144;
    ushort* Wot = Wvt + 262144;
    ushort* Pws = Wot + 262144;           // packed triangular P (bf16), 69 MB

    const size_t need = (size_t)((char*)(Pws + kPwsElems) - (char*)d_ws);

    convw_kernel<<<dim3(8, 8, 5), 256, 0, stream>>>(Wq, Wk, Wv, Wo, E,
                                                    Wqt, Wkt, Wvt, Wot, eb);
    gemm_qkv_kernel<<<dim3(64, 16, 3), 256, 0, stream>>>(q_in, k_in, v_in,
                                                         Wqt, Wkt, Wvt,
                                                         bq, bk, bv, qh, kh, vt);
    if (ws_size >= need) {
        attn_ps_kernel<<<dim3(16, 128), 256, 0, stream>>>(qh, kh, vt, eb,
                                                          attn, ohb, Pws);
    } else {
        attn_fused_kernel<<<dim3(16, 128), 256, 0, stream>>>(qh, kh, vt, eb,
                                                             attn, ohb);
    }
    gemm_o_kernel<<<dim3(64, 16), 256, 0, stream>>>(ohb, Wot, bo, out);
}